// Round 2
// baseline (750.744 us; speedup 1.0000x reference)
//
#include <hip/hip_runtime.h>
#include <cstdint>

// Problem constants (match reference setup_inputs)
static constexpr int NU = 12000;
static constexpr int NI = 12000;
static constexpr int L  = 5;
static constexpr float LAMBDA = 0.01f;   // LAMBDA_U == LAMBDA_V

static constexpr int CGRP = NI / 4;                 // 3000 float4-column groups
static constexpr int NR_SPLIT = 256;                // row-parallel split
static constexpr int LOSS_BLOCKS = CGRP * NR_SPLIT / 256;   // 3000
static constexpr int REG_BLOCKS = 32;

// ---------------------------------------------------------------------------
// Fused kernel. Block roles:
//   [0, LOSS_BLOCKS)                       : masked SSE over R (576 MB stream)
//   [LOSS_BLOCKS, LOSS_BLOCKS+pred_blocks) : 1M gathered 4-dim dots (L2-resident)
//   [.., +REG_BLOCKS)                      : sum U^2 + V^2 partials
// Loss path: each thread owns 4 consecutive columns (20 V floats in regs),
// strides rows by 256, unrolled x2 so two 16B R loads are in flight.
// ---------------------------------------------------------------------------
__global__ __launch_bounds__(256) void pmf_fused_kernel(
        const float* __restrict__ U, const float* __restrict__ V,
        const float* __restrict__ R,
        const int* __restrict__ u_idx, const int* __restrict__ v_idx,
        float* __restrict__ out, int np,
        double* __restrict__ partial_main, double* __restrict__ partial_reg,
        int pred_blocks) {
    const int b = blockIdx.x;

    if (b < LOSS_BLOCKS) {
        // ----------------- masked SSE loss over R -----------------
        const int gid = b * 256 + threadIdx.x;
        const int c  = gid % CGRP;      // float4 col group -> cols 4c..4c+3
        const int r0 = gid / CGRP;      // starting row (0..255)

        float vv[20];
        {
            const float4* vb = reinterpret_cast<const float4*>(V + 20 * (size_t)c);
#pragma unroll
            for (int k = 0; k < 5; ++k) {
                float4 t = vb[k];
                vv[4*k+0] = t.x; vv[4*k+1] = t.y; vv[4*k+2] = t.z; vv[4*k+3] = t.w;
            }
        }

        double acc = 0.0;
        const size_t rstr = (size_t)NR_SPLIT * CGRP;   // float4 units
        const float4* Rp = reinterpret_cast<const float4*>(R) + (size_t)r0 * CGRP + c;
        int i = r0;

        // unroll-2: both R loads + both U rows issued before compute
        for (; i + NR_SPLIT < NU; i += 2 * NR_SPLIT, Rp += 2 * rstr) {
            const float4 ra = Rp[0];
            const float4 rb = Rp[rstr];
            const float* Ua = U + (size_t)i * L;
            const float* Ub = U + (size_t)(i + NR_SPLIT) * L;
            const float a0 = Ua[0], a1 = Ua[1], a2 = Ua[2], a3 = Ua[3], a4 = Ua[4];
            const float b0 = Ub[0], b1 = Ub[1], b2 = Ub[2], b3 = Ub[3], b4 = Ub[4];

            float da0 = a0*vv[0]  + a1*vv[1]  + a2*vv[2]  + a3*vv[3]  + a4*vv[4];
            float da1 = a0*vv[5]  + a1*vv[6]  + a2*vv[7]  + a3*vv[8]  + a4*vv[9];
            float da2 = a0*vv[10] + a1*vv[11] + a2*vv[12] + a3*vv[13] + a4*vv[14];
            float da3 = a0*vv[15] + a1*vv[16] + a2*vv[17] + a3*vv[18] + a4*vv[19];
            float db0 = b0*vv[0]  + b1*vv[1]  + b2*vv[2]  + b3*vv[3]  + b4*vv[4];
            float db1 = b0*vv[5]  + b1*vv[6]  + b2*vv[7]  + b3*vv[8]  + b4*vv[9];
            float db2 = b0*vv[10] + b1*vv[11] + b2*vv[12] + b3*vv[13] + b4*vv[14];
            float db3 = b0*vv[15] + b1*vv[16] + b2*vv[17] + b3*vv[18] + b4*vv[19];

            float e;
            float s = 0.0f;
            e = ra.x - da0; s += (ra.x != 0.0f) ? e*e : 0.0f;
            e = ra.y - da1; s += (ra.y != 0.0f) ? e*e : 0.0f;
            e = ra.z - da2; s += (ra.z != 0.0f) ? e*e : 0.0f;
            e = ra.w - da3; s += (ra.w != 0.0f) ? e*e : 0.0f;
            e = rb.x - db0; s += (rb.x != 0.0f) ? e*e : 0.0f;
            e = rb.y - db1; s += (rb.y != 0.0f) ? e*e : 0.0f;
            e = rb.z - db2; s += (rb.z != 0.0f) ? e*e : 0.0f;
            e = rb.w - db3; s += (rb.w != 0.0f) ? e*e : 0.0f;
            acc += (double)s;
        }
        if (i < NU) {   // tail row
            const float4 ra = Rp[0];
            const float* Ua = U + (size_t)i * L;
            const float a0 = Ua[0], a1 = Ua[1], a2 = Ua[2], a3 = Ua[3], a4 = Ua[4];
            float da0 = a0*vv[0]  + a1*vv[1]  + a2*vv[2]  + a3*vv[3]  + a4*vv[4];
            float da1 = a0*vv[5]  + a1*vv[6]  + a2*vv[7]  + a3*vv[8]  + a4*vv[9];
            float da2 = a0*vv[10] + a1*vv[11] + a2*vv[12] + a3*vv[13] + a4*vv[14];
            float da3 = a0*vv[15] + a1*vv[16] + a2*vv[17] + a3*vv[18] + a4*vv[19];
            float e; float s = 0.0f;
            e = ra.x - da0; s += (ra.x != 0.0f) ? e*e : 0.0f;
            e = ra.y - da1; s += (ra.y != 0.0f) ? e*e : 0.0f;
            e = ra.z - da2; s += (ra.z != 0.0f) ? e*e : 0.0f;
            e = ra.w - da3; s += (ra.w != 0.0f) ? e*e : 0.0f;
            acc += (double)s;
        }

#pragma unroll
        for (int off = 32; off > 0; off >>= 1) acc += __shfl_down(acc, off);
        __shared__ double sacc[4];
        const int lane = threadIdx.x & 63, w = threadIdx.x >> 6;
        if (lane == 0) sacc[w] = acc;
        __syncthreads();
        if (threadIdx.x == 0)
            partial_main[b] = sacc[0] + sacc[1] + sacc[2] + sacc[3];

    } else if (b < LOSS_BLOCKS + pred_blocks) {
        // ----------------- 1M gathered predictions, x4 per thread -----------------
        const int t = (b - LOSS_BLOCKS) * 256 + threadIdx.x;
        const int base = t * 4;
        if (base < np) {
            const int4 ui = *reinterpret_cast<const int4*>(u_idx + base);
            const int4 vi = *reinterpret_cast<const int4*>(v_idx + base);
#pragma unroll
            for (int k = 0; k < 4; ++k) {
                const int p = base + k;
                if (p < np) {
                    const int u = (k == 0) ? ui.x : (k == 1) ? ui.y : (k == 2) ? ui.z : ui.w;
                    const int v = (k == 0) ? vi.x : (k == 1) ? vi.y : (k == 2) ? vi.z : vi.w;
                    const float* up = U + (size_t)u * L;
                    const float* vp = V + (size_t)v * L;
                    out[1 + p] = up[0]*vp[0] + up[1]*vp[1] + up[2]*vp[2] + up[3]*vp[3];
                }
            }
        }

    } else {
        // ----------------- lambda regularizer partials -----------------
        const int rb = b - LOSS_BLOCKS - pred_blocks;
        const int gid = rb * 256 + threadIdx.x;
        const int n4 = (NU * L) / 4;   // 15000 float4 per matrix
        double acc = 0.0;
        const float4* Uf = reinterpret_cast<const float4*>(U);
        const float4* Vf = reinterpret_cast<const float4*>(V);
        for (int k = gid; k < n4; k += REG_BLOCKS * 256) {
            float4 a = Uf[k];
            float4 v = Vf[k];
            acc += (double)(a.x*a.x + a.y*a.y + a.z*a.z + a.w*a.w
                          + v.x*v.x + v.y*v.y + v.z*v.z + v.w*v.w);
        }
#pragma unroll
        for (int off = 32; off > 0; off >>= 1) acc += __shfl_down(acc, off);
        __shared__ double sacc[4];
        const int lane = threadIdx.x & 63, w = threadIdx.x >> 6;
        if (lane == 0) sacc[w] = acc;
        __syncthreads();
        if (threadIdx.x == 0)
            partial_reg[rb] = sacc[0] + sacc[1] + sacc[2] + sacc[3];
    }
}

// ---------------------------------------------------------------------------
// finalize: loss = sum(partial_main) + LAMBDA * (sum U^2 + sum V^2)
// ---------------------------------------------------------------------------
__global__ __launch_bounds__(256) void finalize_kernel(
        const double* __restrict__ partial_main,
        const double* __restrict__ partial_reg,
        float* __restrict__ out) {
    double acc = 0.0;
    for (int k = threadIdx.x; k < LOSS_BLOCKS; k += 256) acc += partial_main[k];
    double reg = 0.0;
    for (int k = threadIdx.x; k < REG_BLOCKS; k += 256) reg += partial_reg[k];
    acc += (double)LAMBDA * reg;
#pragma unroll
    for (int off = 32; off > 0; off >>= 1) acc += __shfl_down(acc, off);
    __shared__ double sacc[4];
    const int lane = threadIdx.x & 63, w = threadIdx.x >> 6;
    if (lane == 0) sacc[w] = acc;
    __syncthreads();
    if (threadIdx.x == 0)
        out[0] = (float)(sacc[0] + sacc[1] + sacc[2] + sacc[3]);
}

extern "C" void kernel_launch(void* const* d_in, const int* in_sizes, int n_in,
                              void* d_out, int out_size, void* d_ws, size_t ws_size,
                              hipStream_t stream) {
    const float* U = (const float*)d_in[0];
    const float* V = (const float*)d_in[1];
    const float* R = (const float*)d_in[2];
    const int* u_idx = (const int*)d_in[3];
    const int* v_idx = (const int*)d_in[4];
    float* out = (float*)d_out;
    const int np = in_sizes[3];

    double* partial_main = (double*)d_ws;               // [LOSS_BLOCKS]
    double* partial_reg  = partial_main + LOSS_BLOCKS;  // [REG_BLOCKS]

    const int pred_blocks = (np / 4 + 255) / 256;       // 977 for np=1e6
    const int total_blocks = LOSS_BLOCKS + pred_blocks + REG_BLOCKS;

    pmf_fused_kernel<<<total_blocks, 256, 0, stream>>>(
        U, V, R, u_idx, v_idx, out, np, partial_main, partial_reg, pred_blocks);
    finalize_kernel<<<1, 256, 0, stream>>>(partial_main, partial_reg, out);
}